// Round 2
// baseline (560.158 us; speedup 1.0000x reference)
//
#include <hip/hip_runtime.h>

#define NN 8192
#define DD 128

typedef short s16x4 __attribute__((ext_vector_type(4)));
typedef short s16x8 __attribute__((ext_vector_type(8)));
typedef float f32x4 __attribute__((ext_vector_type(4)));
typedef unsigned short u16;
typedef const void __attribute__((address_space(1))) gvoid;
typedef void __attribute__((address_space(3))) lvoid;

__device__ __forceinline__ u16 f2bf(float f) {
  unsigned int u = __float_as_uint(f);
  u += 0x7fffu + ((u >> 16) & 1u);   // RNE; inputs are never NaN
  return (u16)(u >> 16);
}
__device__ __forceinline__ float bf2f(u16 h) {
  return __uint_as_float(((unsigned int)h) << 16);
}

// ---- K1: dinv[i] = rsqrt(1 + rowsum(A[i,:]))  AND  Abf = bf16(A) ----
// Also zeroes the split-K arrival counters (must happen every iteration,
// after the harness poison fill, before k_gemm).
__global__ __launch_bounds__(256) void k_prep(const float* __restrict__ A,
                                              float* __restrict__ dinv,
                                              u16* __restrict__ Abf,
                                              unsigned int* __restrict__ cnt) {
  const int row = blockIdx.x;
  if (row < 64 && threadIdx.x == 0) cnt[row] = 0u;
  const float4* Ar = (const float4*)(A + (size_t)row * NN);
  ushort4* Br = (ushort4*)(Abf + (size_t)row * NN);
  const int t = threadIdx.x;
  float s = 0.f;
#pragma unroll
  for (int i = 0; i < 8; ++i) {
    float4 v = Ar[t + 256 * i];
    s += (v.x + v.y) + (v.z + v.w);
    ushort4 b;
    b.x = f2bf(v.x); b.y = f2bf(v.y); b.z = f2bf(v.z); b.w = f2bf(v.w);
    Br[t + 256 * i] = b;
  }
#pragma unroll
  for (int off = 32; off > 0; off >>= 1) s += __shfl_down(s, off, 64);
  __shared__ float red[4];
  if ((t & 63) == 0) red[t >> 6] = s;
  __syncthreads();
  if (t == 0) {
    float d = 1.0f + ((red[0] + red[1]) + (red[2] + red[3]));
    dinv[row] = d > 0.f ? rsqrtf(d) : 0.f;
  }
}

// ---- K2: tT[n][j] = bf16( dinv[j] * (X @ W)[j][n] ), plus row-major copy tR[j][n] ----
__global__ __launch_bounds__(256) void k_support(const float* __restrict__ X,
                                                 const float* __restrict__ W,
                                                 const float* __restrict__ dinv,
                                                 u16* __restrict__ tT,
                                                 u16* __restrict__ tR) {
  __shared__ __align__(16) u16 Wt[128][136];  // Wt[n][k] = W[k][n]
  __shared__ __align__(16) u16 Xs[32][136];   // Xs[j][k]
  const int t = threadIdx.x;
  const int j0 = blockIdx.x * 32;

  const float4* W4 = (const float4*)W;
#pragma unroll
  for (int s = 0; s < 16; ++s) {
    int c = t + 256 * s;
    int k = c >> 5, n4 = c & 31;
    float4 wv = W4[c];
    Wt[n4 * 4 + 0][k] = f2bf(wv.x);
    Wt[n4 * 4 + 1][k] = f2bf(wv.y);
    Wt[n4 * 4 + 2][k] = f2bf(wv.z);
    Wt[n4 * 4 + 3][k] = f2bf(wv.w);
  }
  const float4* X4 = (const float4*)(X + (size_t)j0 * DD);
#pragma unroll
  for (int s = 0; s < 4; ++s) {
    int c = t + 256 * s;
    int j = c >> 5, q = c & 31;
    float4 xv = X4[c];
    s16x4 p;
    p[0] = (short)f2bf(xv.x); p[1] = (short)f2bf(xv.y);
    p[2] = (short)f2bf(xv.z); p[3] = (short)f2bf(xv.w);
    *(s16x4*)&Xs[j][q * 4] = p;
  }
  __syncthreads();

  const int w = t >> 6, L = t & 63, lrow = L & 15, quad = L >> 4;
  f32x4 acc[2][2] = {};
#pragma unroll
  for (int ks = 0; ks < 4; ++ks) {
    const int k = ks * 32;
    s16x8 fa[2], fb[2];
#pragma unroll
    for (int nt = 0; nt < 2; ++nt)
      fa[nt] = *(const s16x8*)&Wt[w * 32 + nt * 16 + lrow][k + quad * 8];
#pragma unroll
    for (int jt = 0; jt < 2; ++jt)
      fb[jt] = *(const s16x8*)&Xs[jt * 16 + lrow][k + quad * 8];
#pragma unroll
    for (int nt = 0; nt < 2; ++nt)
#pragma unroll
      for (int jt = 0; jt < 2; ++jt)
        acc[nt][jt] = __builtin_amdgcn_mfma_f32_16x16x32_bf16(fa[nt], fb[jt], acc[nt][jt], 0, 0, 0);
  }

#pragma unroll
  for (int jt = 0; jt < 2; ++jt) {
    const int j = j0 + jt * 16 + lrow;
    const float dv = dinv[j];
#pragma unroll
    for (int nt = 0; nt < 2; ++nt) {
#pragma unroll
      for (int r = 0; r < 4; ++r) {
        const int n = w * 32 + nt * 16 + quad * 4 + r;
        const u16 v = f2bf(dv * acc[nt][jt][r]);
        tT[(size_t)n * NN + j] = v;
        tR[(size_t)j * DD + n] = v;
      }
    }
  }
}

// ---- K3: fused split-K GEMM + fixup reduce ----
// part[kq] = Abf[128 rows, keighth] @ tT[:, keighth]^T  (split-K=8)
// BM=128, BN=128, BK=64; per-wave 64x64 output (acc[4][4], 0.5 ds_read/MFMA).
// After storing its slice, each block does threadfence + agent-scope
// atomicAdd(cnt[bm]); the 8th arrival reduces all 8 slices (own from acc
// registers, 7 from L2/L3-warm part), applies dinv_i, diag (tR), bias, and
// writes out. Deadlock-free: no spinning.
__global__ __launch_bounds__(256, 2) void k_gemm(const u16* __restrict__ Abf,
                                                 const u16* __restrict__ tT,
                                                 const u16* __restrict__ tR,
                                                 const float* __restrict__ dinv,
                                                 const float* __restrict__ bias,
                                                 float* __restrict__ part,
                                                 unsigned int* __restrict__ cnt,
                                                 float* __restrict__ out) {
  __shared__ __align__(16) unsigned char sh[2][32768];
  const int t = threadIdx.x;
  const int bm = blockIdx.x >> 3;       // 0..63 (128-row block)
  const int kq = blockIdx.x & 7;        // split-K eighth
  const int kbase = kq * (NN / 8);      // 1024-wide K chunk
  const int w = t >> 6, L = t & 63, lrow = L & 15, quad = L >> 4;
  const int wr = w >> 1, wc = w & 1;    // wave 2x2 -> 64x64 patch each
  const size_t row0 = (size_t)bm * 128;

  auto prefetch = [&](int buf, int k0) {
#pragma unroll
    for (int j = 0; j < 8; ++j) {
      const int g = w * 8 + j;                 // wave-uniform issue id, 0..31
      const int o = g * 1024 + L * 16;         // byte offset in tile image
      const u16* src;
      if (g < 16) {                            // A region (first 16KB, 128 rows)
        const int r = o >> 7, c = (o >> 4) & 7;
        src = Abf + (row0 + r) * NN + (k0 + ((c ^ (r & 7)) << 3));
      } else {                                 // B region (16KB, 128 rows)
        const int o2 = o - 16384;
        const int r = o2 >> 7, c = (o2 >> 4) & 7;
        src = tT + (size_t)r * NN + (k0 + ((c ^ (r & 7)) << 3));
      }
      __builtin_amdgcn_global_load_lds((gvoid*)src,
                                       (lvoid*)&sh[buf][g * 1024], 16, 0, 0);
    }
  };

  f32x4 acc[4][4] = {};
  prefetch(0, kbase);
  __syncthreads();

  for (int it = 0; it < 16; ++it) {
    const int cur = it & 1;
    if (it < 15) prefetch(cur ^ 1, kbase + (it + 1) * 64);
    const unsigned char* Ab = &sh[cur][0];
    const unsigned char* Bb = &sh[cur][16384];
#pragma unroll
    for (int s = 0; s < 2; ++s) {
      const int cx = (((s * 4) | quad) ^ (lrow & 7)) << 4;  // swizzled chunk
      s16x8 fb[4];
#pragma unroll
      for (int nt = 0; nt < 4; ++nt)
        fb[nt] = *(const s16x8*)(Bb + (wc * 64 + nt * 16 + lrow) * 128 + cx);
#pragma unroll
      for (int mt = 0; mt < 4; ++mt) {
        s16x8 fa = *(const s16x8*)(Ab + (wr * 64 + mt * 16 + lrow) * 128 + cx);
#pragma unroll
        for (int nt = 0; nt < 4; ++nt)
          acc[mt][nt] = __builtin_amdgcn_mfma_f32_16x16x32_bf16(fa, fb[nt], acc[mt][nt], 0, 0, 0);
      }
    }
    __syncthreads();
  }

  // -- store own slice --
  float* pbase = part + (size_t)kq * NN * DD;
#pragma unroll
  for (int mt = 0; mt < 4; ++mt) {
#pragma unroll
    for (int r = 0; r < 4; ++r) {
      const int i = (int)row0 + wr * 64 + mt * 16 + quad * 4 + r;
#pragma unroll
      for (int nt = 0; nt < 4; ++nt) {
        const int n = wc * 64 + nt * 16 + lrow;
        pbase[(size_t)i * DD + n] = acc[mt][nt][r];
      }
    }
  }

  // -- split-K fixup: last-arriving block reduces --
  __threadfence();
  __shared__ unsigned int lastf;
  if (t == 0) {
    unsigned int prev = __hip_atomic_fetch_add(&cnt[bm], 1u, __ATOMIC_ACQ_REL,
                                               __HIP_MEMORY_SCOPE_AGENT);
    lastf = (prev == 7u) ? 1u : 0u;
  }
  __syncthreads();
  if (lastf == 0u) return;
  __threadfence();  // acquire: make remote slices visible

#pragma unroll
  for (int mt = 0; mt < 4; ++mt) {
#pragma unroll
    for (int r = 0; r < 4; ++r) {
      const int i = (int)row0 + wr * 64 + mt * 16 + quad * 4 + r;
      const float dv = dinv[i];
#pragma unroll
      for (int nt = 0; nt < 4; ++nt) {
        const int n = wc * 64 + nt * 16 + lrow;
        const size_t off = (size_t)i * DD + n;
        float q[8];
#pragma unroll
        for (int kk = 0; kk < 8; ++kk)
          q[kk] = (kk == kq) ? acc[mt][nt][r]
                             : part[(size_t)kk * NN * DD + off];
        const float s = ((q[0] + q[1]) + (q[2] + q[3])) +
                        ((q[4] + q[5]) + (q[6] + q[7]));
        out[off] = dv * (s + bf2f(tR[off])) + bias[n];
      }
    }
  }
}

extern "C" void kernel_launch(void* const* d_in, const int* in_sizes, int n_in,
                              void* d_out, int out_size, void* d_ws, size_t ws_size,
                              hipStream_t stream) {
  const float* X    = (const float*)d_in[0];   // node_features [8192,128]
  const float* A    = (const float*)d_in[1];   // adj_matrix    [8192,8192]
  const float* W    = (const float*)d_in[2];   // weight        [128,128]
  const float* bias = (const float*)d_in[3];   // bias          [128]
  float* out = (float*)d_out;

  char* ws = (char*)d_ws;
  float* dinv        = (float*)ws;                          // 32 KB
  u16*   tT          = (u16*)(ws + 32768);                  // 2 MB
  u16*   tR          = (u16*)(ws + 32768 + 2097152);        // 2 MB
  float* part        = (float*)(ws + 32768 + 2*2097152);    // 32 MB (8 slices)
  u16*   Abf         = (u16*)(ws + 32768 + 2*2097152 + 33554432);   // 128 MB
  unsigned int* cnt  = (unsigned int*)(ws + 32768 + 2*2097152 + 33554432
                                          + 134217728);     // 256 B

  hipLaunchKernelGGL(k_prep,    dim3(8192), dim3(256), 0, stream, A, dinv, Abf, cnt);
  hipLaunchKernelGGL(k_support, dim3(256),  dim3(256), 0, stream, X, W, dinv, tT, tR);
  hipLaunchKernelGGL(k_gemm,    dim3(512),  dim3(256), 0, stream,
                     Abf, tT, tR, dinv, bias, part, cnt, out);
}

// Round 3
// 427.545 us; speedup vs baseline: 1.3102x; 1.3102x over previous
//
#include <hip/hip_runtime.h>

#define NN 8192
#define DD 128

typedef short s16x4 __attribute__((ext_vector_type(4)));
typedef short s16x8 __attribute__((ext_vector_type(8)));
typedef float f32x4 __attribute__((ext_vector_type(4)));
typedef unsigned short u16;
typedef const void __attribute__((address_space(1))) gvoid;
typedef void __attribute__((address_space(3))) lvoid;

__device__ __forceinline__ u16 f2bf(float f) {
  unsigned int u = __float_as_uint(f);
  u += 0x7fffu + ((u >> 16) & 1u);   // RNE; inputs are never NaN
  return (u16)(u >> 16);
}
__device__ __forceinline__ float bf2f(u16 h) {
  return __uint_as_float(((unsigned int)h) << 16);
}

// ---- K1: dinv[i] = rsqrt(1 + rowsum(A[i,:]))  AND  Abf = bf16(A) ----
__global__ __launch_bounds__(256) void k_prep(const float* __restrict__ A,
                                              float* __restrict__ dinv,
                                              u16* __restrict__ Abf) {
  const int row = blockIdx.x;
  const float4* Ar = (const float4*)(A + (size_t)row * NN);
  ushort4* Br = (ushort4*)(Abf + (size_t)row * NN);
  const int t = threadIdx.x;
  float s = 0.f;
#pragma unroll
  for (int i = 0; i < 8; ++i) {
    float4 v = Ar[t + 256 * i];
    s += (v.x + v.y) + (v.z + v.w);
    ushort4 b;
    b.x = f2bf(v.x); b.y = f2bf(v.y); b.z = f2bf(v.z); b.w = f2bf(v.w);
    Br[t + 256 * i] = b;
  }
#pragma unroll
  for (int off = 32; off > 0; off >>= 1) s += __shfl_down(s, off, 64);
  __shared__ float red[4];
  if ((t & 63) == 0) red[t >> 6] = s;
  __syncthreads();
  if (t == 0) {
    float d = 1.0f + ((red[0] + red[1]) + (red[2] + red[3]));
    dinv[row] = d > 0.f ? rsqrtf(d) : 0.f;
  }
}

// ---- K2: tT[n][j] = bf16( dinv[j] * (X @ W)[j][n] ) ----
__global__ __launch_bounds__(256) void k_support(const float* __restrict__ X,
                                                 const float* __restrict__ W,
                                                 const float* __restrict__ dinv,
                                                 u16* __restrict__ tT) {
  __shared__ __align__(16) u16 Wt[128][136];  // Wt[n][k] = W[k][n]
  __shared__ __align__(16) u16 Xs[32][136];   // Xs[j][k]
  const int t = threadIdx.x;
  const int j0 = blockIdx.x * 32;

  const float4* W4 = (const float4*)W;
#pragma unroll
  for (int s = 0; s < 16; ++s) {
    int c = t + 256 * s;
    int k = c >> 5, n4 = c & 31;
    float4 wv = W4[c];
    Wt[n4 * 4 + 0][k] = f2bf(wv.x);
    Wt[n4 * 4 + 1][k] = f2bf(wv.y);
    Wt[n4 * 4 + 2][k] = f2bf(wv.z);
    Wt[n4 * 4 + 3][k] = f2bf(wv.w);
  }
  const float4* X4 = (const float4*)(X + (size_t)j0 * DD);
#pragma unroll
  for (int s = 0; s < 4; ++s) {
    int c = t + 256 * s;
    int j = c >> 5, q = c & 31;
    float4 xv = X4[c];
    s16x4 p;
    p[0] = (short)f2bf(xv.x); p[1] = (short)f2bf(xv.y);
    p[2] = (short)f2bf(xv.z); p[3] = (short)f2bf(xv.w);
    *(s16x4*)&Xs[j][q * 4] = p;
  }
  __syncthreads();

  const int w = t >> 6, L = t & 63, lrow = L & 15, quad = L >> 4;
  f32x4 acc[2][2] = {};
#pragma unroll
  for (int ks = 0; ks < 4; ++ks) {
    const int k = ks * 32;
    s16x8 fa[2], fb[2];
#pragma unroll
    for (int nt = 0; nt < 2; ++nt)
      fa[nt] = *(const s16x8*)&Wt[w * 32 + nt * 16 + lrow][k + quad * 8];
#pragma unroll
    for (int jt = 0; jt < 2; ++jt)
      fb[jt] = *(const s16x8*)&Xs[jt * 16 + lrow][k + quad * 8];
#pragma unroll
    for (int nt = 0; nt < 2; ++nt)
#pragma unroll
      for (int jt = 0; jt < 2; ++jt)
        acc[nt][jt] = __builtin_amdgcn_mfma_f32_16x16x32_bf16(fa[nt], fb[jt], acc[nt][jt], 0, 0, 0);
  }

#pragma unroll
  for (int jt = 0; jt < 2; ++jt) {
    const int j = j0 + jt * 16 + lrow;
    const float dv = dinv[j];
#pragma unroll
    for (int nt = 0; nt < 2; ++nt) {
#pragma unroll
      for (int r = 0; r < 4; ++r) {
        const int n = w * 32 + nt * 16 + quad * 4 + r;
        tT[(size_t)n * NN + j] = f2bf(dv * acc[nt][jt][r]);
      }
    }
  }
}

// ---- K3: part[kq] = Abf[128 rows, keighth] @ tT[:, keighth]^T  (split-K=8) ----
// BM=128, BN=128, BK=64. Tile image: A 128x128B (16KB) + B 128x128B (16KB) = 32KB,
// double-buffered = 64KB LDS (2 blocks/CU = 128KB). Per-wave output 64x64
// (acc[4][4]) -> 16 ds_read_b128 per 32 MFMA (0.5/MFMA, m97 ratio).
// 16B chunks XOR-swizzled (chunk ^= row&7) since row stride 128B == 32 banks.
// Grid 512 = 64 row-blocks x 8 kq; round-robin XCD %8 => each XCD sees one kq,
// so its 256KB tT chunk is L2-resident.
// NOTE (R2 lesson): do NOT fuse the split-K reduce in here. Device-scope
// fence + atomic per block forces per-XCD L2 writeback on gfx950 -> k_gemm
// went 25us -> 193us (620 GB/s, MfmaUtil 3.4%). Kernel boundary is cheaper.
__global__ __launch_bounds__(256, 2) void k_gemm(const u16* __restrict__ Abf,
                                                 const u16* __restrict__ tT,
                                                 float* __restrict__ part) {
  __shared__ __align__(16) unsigned char sh[2][32768];
  const int t = threadIdx.x;
  const int bm = blockIdx.x >> 3;       // 0..63 (128-row block)
  const int kq = blockIdx.x & 7;        // split-K eighth
  const int kbase = kq * (NN / 8);      // 1024-wide K chunk
  const int w = t >> 6, L = t & 63, lrow = L & 15, quad = L >> 4;
  const int wr = w >> 1, wc = w & 1;    // wave 2x2 -> 64x64 patch each
  const size_t row0 = (size_t)bm * 128;

  auto prefetch = [&](int buf, int k0) {
#pragma unroll
    for (int j = 0; j < 8; ++j) {
      const int g = w * 8 + j;                 // wave-uniform issue id, 0..31
      const int o = g * 1024 + L * 16;         // byte offset in tile image
      const u16* src;
      if (g < 16) {                            // A region (first 16KB, 128 rows)
        const int r = o >> 7, c = (o >> 4) & 7;
        src = Abf + (row0 + r) * NN + (k0 + ((c ^ (r & 7)) << 3));
      } else {                                 // B region (16KB, 128 rows)
        const int o2 = o - 16384;
        const int r = o2 >> 7, c = (o2 >> 4) & 7;
        src = tT + (size_t)r * NN + (k0 + ((c ^ (r & 7)) << 3));
      }
      __builtin_amdgcn_global_load_lds((gvoid*)src,
                                       (lvoid*)&sh[buf][g * 1024], 16, 0, 0);
    }
  };

  f32x4 acc[4][4] = {};
  prefetch(0, kbase);
  __syncthreads();

  for (int it = 0; it < 16; ++it) {
    const int cur = it & 1;
    if (it < 15) prefetch(cur ^ 1, kbase + (it + 1) * 64);
    const unsigned char* Ab = &sh[cur][0];
    const unsigned char* Bb = &sh[cur][16384];
#pragma unroll
    for (int s = 0; s < 2; ++s) {
      const int cx = (((s * 4) | quad) ^ (lrow & 7)) << 4;  // swizzled chunk
      s16x8 fb[4];
#pragma unroll
      for (int nt = 0; nt < 4; ++nt)
        fb[nt] = *(const s16x8*)(Bb + (wc * 64 + nt * 16 + lrow) * 128 + cx);
#pragma unroll
      for (int mt = 0; mt < 4; ++mt) {
        s16x8 fa = *(const s16x8*)(Ab + (wr * 64 + mt * 16 + lrow) * 128 + cx);
#pragma unroll
        for (int nt = 0; nt < 4; ++nt)
          acc[mt][nt] = __builtin_amdgcn_mfma_f32_16x16x32_bf16(fa, fb[nt], acc[mt][nt], 0, 0, 0);
      }
    }
    __syncthreads();
  }

  float* pbase = part + (size_t)kq * NN * DD;
#pragma unroll
  for (int mt = 0; mt < 4; ++mt) {
#pragma unroll
    for (int r = 0; r < 4; ++r) {
      const int i = (int)row0 + wr * 64 + mt * 16 + quad * 4 + r;
#pragma unroll
      for (int nt = 0; nt < 4; ++nt) {
        const int n = wc * 64 + nt * 16 + lrow;
        pbase[(size_t)i * DD + n] = acc[mt][nt][r];
      }
    }
  }
}

// ---- K4: out[i][n] = dinv[i]*(sum_q part[q] + diag) + bias[n] ----
__global__ __launch_bounds__(256) void k_reduce(const float* __restrict__ part,
                                                const u16* __restrict__ tT,
                                                const float* __restrict__ dinv,
                                                const float* __restrict__ bias,
                                                float* __restrict__ out) {
  const int gid = blockIdx.x * 256 + threadIdx.x;   // 0 .. 262143
  const int i = gid >> 5;
  const int c = gid & 31;                            // n = 4c .. 4c+3
  const size_t idx = (size_t)i * 32 + c;
  float4 p[8];
#pragma unroll
  for (int q = 0; q < 8; ++q)
    p[q] = ((const float4*)(part + (size_t)q * NN * DD))[idx];
  float4 s;
  s.x = ((p[0].x + p[1].x) + (p[2].x + p[3].x)) + ((p[4].x + p[5].x) + (p[6].x + p[7].x));
  s.y = ((p[0].y + p[1].y) + (p[2].y + p[3].y)) + ((p[4].y + p[5].y) + (p[6].y + p[7].y));
  s.z = ((p[0].z + p[1].z) + (p[2].z + p[3].z)) + ((p[4].z + p[5].z) + (p[6].z + p[7].z));
  s.w = ((p[0].w + p[1].w) + (p[2].w + p[3].w)) + ((p[4].w + p[5].w) + (p[6].w + p[7].w));
  const float4 bb = ((const float4*)bias)[c];
  const float dv = dinv[i];
  const int n = c * 4;
  float4 o;
  o.x = dv * (s.x + bf2f(tT[(size_t)(n + 0) * NN + i])) + bb.x;
  o.y = dv * (s.y + bf2f(tT[(size_t)(n + 1) * NN + i])) + bb.y;
  o.z = dv * (s.z + bf2f(tT[(size_t)(n + 2) * NN + i])) + bb.z;
  o.w = dv * (s.w + bf2f(tT[(size_t)(n + 3) * NN + i])) + bb.w;
  ((float4*)out)[idx] = o;
}

extern "C" void kernel_launch(void* const* d_in, const int* in_sizes, int n_in,
                              void* d_out, int out_size, void* d_ws, size_t ws_size,
                              hipStream_t stream) {
  const float* X    = (const float*)d_in[0];   // node_features [8192,128]
  const float* A    = (const float*)d_in[1];   // adj_matrix    [8192,8192]
  const float* W    = (const float*)d_in[2];   // weight        [128,128]
  const float* bias = (const float*)d_in[3];   // bias          [128]
  float* out = (float*)d_out;

  float* dinv = (float*)d_ws;                                        // 32 KB
  u16*   tT   = (u16*)((char*)d_ws + 32768);                         // 2 MB
  float* part = (float*)((char*)d_ws + 32768 + 2097152);             // 32 MB (8 slices)
  u16*   Abf  = (u16*)((char*)d_ws + 32768 + 2097152 + 33554432);    // 128 MB

  hipLaunchKernelGGL(k_prep,    dim3(8192), dim3(256), 0, stream, A, dinv, Abf);
  hipLaunchKernelGGL(k_support, dim3(256),  dim3(256), 0, stream, X, W, dinv, tT);
  hipLaunchKernelGGL(k_gemm,    dim3(512),  dim3(256), 0, stream, Abf, tT, part);
  hipLaunchKernelGGL(k_reduce,  dim3(1024), dim3(256), 0, stream, part, tT, dinv, bias, out);
}

// Round 4
// 417.831 us; speedup vs baseline: 1.3406x; 1.0232x over previous
//
#include <hip/hip_runtime.h>

#define NN 8192
#define DD 128

typedef short s16x4 __attribute__((ext_vector_type(4)));
typedef short s16x8 __attribute__((ext_vector_type(8)));
typedef float f32x4 __attribute__((ext_vector_type(4)));
typedef unsigned short u16;
typedef const void __attribute__((address_space(1))) gvoid;
typedef void __attribute__((address_space(3))) lvoid;

__device__ __forceinline__ u16 f2bf(float f) {
  unsigned int u = __float_as_uint(f);
  u += 0x7fffu + ((u >> 16) & 1u);   // RNE; inputs are never NaN
  return (u16)(u >> 16);
}
__device__ __forceinline__ float bf2f(u16 h) {
  return __uint_as_float(((unsigned int)h) << 16);
}

// ---- K1: dinv[i] = rsqrt(1 + rowsum(A[i,:]))  AND  A8 = round(A*127) u8 ----
// u8 fixed-point: k=round(a*127). Dequant k -> bf16 is EXACT (ints <=127 fit
// bf16 mantissa); the 1/127 scale is folded into k_reduce. A-quant error
// contribution to out ~5e-5 std (vs bf16's 2.4e-4 absmax) -- near-free.
__global__ __launch_bounds__(256) void k_prep(const float* __restrict__ A,
                                              float* __restrict__ dinv,
                                              unsigned char* __restrict__ A8) {
  const int row = blockIdx.x;
  const float4* Ar = (const float4*)(A + (size_t)row * NN);
  unsigned int* Br = (unsigned int*)(A8 + (size_t)row * NN);
  const int t = threadIdx.x;
  float s = 0.f;
#pragma unroll
  for (int i = 0; i < 8; ++i) {
    float4 v = Ar[t + 256 * i];
    s += (v.x + v.y) + (v.z + v.w);
    unsigned a0 = (unsigned)__float2int_rn(v.x * 127.0f);
    unsigned a1 = (unsigned)__float2int_rn(v.y * 127.0f);
    unsigned a2 = (unsigned)__float2int_rn(v.z * 127.0f);
    unsigned a3 = (unsigned)__float2int_rn(v.w * 127.0f);
    Br[t + 256 * i] = a0 | (a1 << 8) | (a2 << 16) | (a3 << 24);
  }
#pragma unroll
  for (int off = 32; off > 0; off >>= 1) s += __shfl_down(s, off, 64);
  __shared__ float red[4];
  if ((t & 63) == 0) red[t >> 6] = s;
  __syncthreads();
  if (t == 0) {
    float d = 1.0f + ((red[0] + red[1]) + (red[2] + red[3]));
    dinv[row] = d > 0.f ? rsqrtf(d) : 0.f;
  }
}

// ---- K2: tT[n][j] = bf16( dinv[j] * (X @ W)[j][n] ) ----
__global__ __launch_bounds__(256) void k_support(const float* __restrict__ X,
                                                 const float* __restrict__ W,
                                                 const float* __restrict__ dinv,
                                                 u16* __restrict__ tT) {
  __shared__ __align__(16) u16 Wt[128][136];  // Wt[n][k] = W[k][n]
  __shared__ __align__(16) u16 Xs[32][136];   // Xs[j][k]
  const int t = threadIdx.x;
  const int j0 = blockIdx.x * 32;

  const float4* W4 = (const float4*)W;
#pragma unroll
  for (int s = 0; s < 16; ++s) {
    int c = t + 256 * s;
    int k = c >> 5, n4 = c & 31;
    float4 wv = W4[c];
    Wt[n4 * 4 + 0][k] = f2bf(wv.x);
    Wt[n4 * 4 + 1][k] = f2bf(wv.y);
    Wt[n4 * 4 + 2][k] = f2bf(wv.z);
    Wt[n4 * 4 + 3][k] = f2bf(wv.w);
  }
  const float4* X4 = (const float4*)(X + (size_t)j0 * DD);
#pragma unroll
  for (int s = 0; s < 4; ++s) {
    int c = t + 256 * s;
    int j = c >> 5, q = c & 31;
    float4 xv = X4[c];
    s16x4 p;
    p[0] = (short)f2bf(xv.x); p[1] = (short)f2bf(xv.y);
    p[2] = (short)f2bf(xv.z); p[3] = (short)f2bf(xv.w);
    *(s16x4*)&Xs[j][q * 4] = p;
  }
  __syncthreads();

  const int w = t >> 6, L = t & 63, lrow = L & 15, quad = L >> 4;
  f32x4 acc[2][2] = {};
#pragma unroll
  for (int ks = 0; ks < 4; ++ks) {
    const int k = ks * 32;
    s16x8 fa[2], fb[2];
#pragma unroll
    for (int nt = 0; nt < 2; ++nt)
      fa[nt] = *(const s16x8*)&Wt[w * 32 + nt * 16 + lrow][k + quad * 8];
#pragma unroll
    for (int jt = 0; jt < 2; ++jt)
      fb[jt] = *(const s16x8*)&Xs[jt * 16 + lrow][k + quad * 8];
#pragma unroll
    for (int nt = 0; nt < 2; ++nt)
#pragma unroll
      for (int jt = 0; jt < 2; ++jt)
        acc[nt][jt] = __builtin_amdgcn_mfma_f32_16x16x32_bf16(fa[nt], fb[jt], acc[nt][jt], 0, 0, 0);
  }

#pragma unroll
  for (int jt = 0; jt < 2; ++jt) {
    const int j = j0 + jt * 16 + lrow;
    const float dv = dinv[j];
#pragma unroll
    for (int nt = 0; nt < 2; ++nt) {
#pragma unroll
      for (int r = 0; r < 4; ++r) {
        const int n = w * 32 + nt * 16 + quad * 4 + r;
        tT[(size_t)n * NN + j] = f2bf(dv * acc[nt][jt][r]);
      }
    }
  }
}

// ---- K3: part[kq] = (127*A)[128 rows, keighth] @ tT[:, keighth]^T  (split-K=8) ----
// Inner loop IDENTICAL to R1/R3 (bf16 LDS image, b128 reads, chunk^row&7
// swizzle, 0 bank conflicts). Only A staging changed: HBM holds u8; each
// thread reg-stages 32 B u8 (loads issued BEFORE B-gloads so the dep-wait is
// vmcnt(16), not 0), converts to bf16 ints (exact: cvt_f32_ubyte + high-16
// perm truncation) after the MFMA phase, ds_writes the same swizzled layout.
// B stays global_load_lds. HBM: 64 MB A + 32 MB part + tT(L2) ~= 98 MB.
// NOTE (R2 lesson): no cross-block fixup fusion -- L2 writeback tax 170us.
__global__ __launch_bounds__(256, 2) void k_gemm(const unsigned char* __restrict__ A8,
                                                 const u16* __restrict__ tT,
                                                 float* __restrict__ part) {
  __shared__ __align__(16) unsigned char sh[2][32768];
  const int t = threadIdx.x;
  const int bm = blockIdx.x >> 3;       // 0..63 (128-row block)
  const int kq = blockIdx.x & 7;        // split-K eighth
  const int kbase = kq * (NN / 8);      // 1024-wide K chunk
  const int w = t >> 6, L = t & 63, lrow = L & 15, quad = L >> 4;
  const int wr = w >> 1, wc = w & 1;    // wave 2x2 -> 64x64 patch each
  const size_t row0 = (size_t)bm * 128;

  // A reg-stage: thread t covers u8 row r = t>>1, 32 B at col (t&1)*32
  const int ar = t >> 1;                // 0..127
  const int ac = (t & 1) * 2;           // u8 16B-chunk index 0 or 2
  uint4 areg0, areg1;
  auto loadA = [&](int k0) {
    const unsigned char* src = A8 + (row0 + ar) * NN + k0 + ac * 16;
    areg0 = *(const uint4*)src;
    areg1 = *(const uint4*)(src + 16);
  };
  auto writeA = [&](int buf) {
    unsigned char* arow = &sh[buf][ar * 128];
#pragma unroll
    for (int i = 0; i < 2; ++i) {
      uint4 v = i ? areg1 : areg0;
      unsigned ww[4] = {v.x, v.y, v.z, v.w};
      unsigned o[8];
#pragma unroll
      for (int q = 0; q < 4; ++q) {
        float f0 = (float)(ww[q] & 0xffu);
        float f1 = (float)((ww[q] >> 8) & 0xffu);
        float f2 = (float)((ww[q] >> 16) & 0xffu);
        float f3 = (float)(ww[q] >> 24);
        // bf16(int k) = high 16 bits of f32(k), exact for k<=255
        o[q * 2 + 0] = __builtin_amdgcn_perm(__float_as_uint(f1), __float_as_uint(f0), 0x07060302u);
        o[q * 2 + 1] = __builtin_amdgcn_perm(__float_as_uint(f3), __float_as_uint(f2), 0x07060302u);
      }
      const int ci = ac + i;            // u8 chunk -> bf16 chunks 2ci, 2ci+1
      *(uint4*)(arow + (((2 * ci + 0) ^ (ar & 7)) << 4)) = make_uint4(o[0], o[1], o[2], o[3]);
      *(uint4*)(arow + (((2 * ci + 1) ^ (ar & 7)) << 4)) = make_uint4(o[4], o[5], o[6], o[7]);
    }
  };
  // B staging via global_load_lds: 16 x 1KB, 4 per wave
  auto prefetchB = [&](int buf, int k0) {
#pragma unroll
    for (int j = 0; j < 4; ++j) {
      const int g = 16 + w * 4 + j;            // B region: sh bytes [16K,32K)
      const int o = (g - 16) * 1024 + L * 16;
      const int r = o >> 7, c = (o >> 4) & 7;
      const u16* src = tT + (size_t)r * NN + (k0 + ((c ^ (r & 7)) << 3));
      __builtin_amdgcn_global_load_lds((gvoid*)src,
                                       (lvoid*)&sh[buf][g * 1024], 16, 0, 0);
    }
  };

  f32x4 acc[4][4] = {};
  loadA(kbase);
  prefetchB(0, kbase);
  writeA(0);
  __syncthreads();

  for (int it = 0; it < 16; ++it) {
    const int cur = it & 1;
    if (it < 15) {
      loadA(kbase + (it + 1) * 64);            // issue first: dep-wait leaves B in flight
      prefetchB(cur ^ 1, kbase + (it + 1) * 64);
    }
    const unsigned char* Ab = &sh[cur][0];
    const unsigned char* Bb = &sh[cur][16384];
#pragma unroll
    for (int s = 0; s < 2; ++s) {
      const int cx = (((s * 4) | quad) ^ (lrow & 7)) << 4;  // swizzled chunk
      s16x8 fb[4];
#pragma unroll
      for (int nt = 0; nt < 4; ++nt)
        fb[nt] = *(const s16x8*)(Bb + (wc * 64 + nt * 16 + lrow) * 128 + cx);
#pragma unroll
      for (int mt = 0; mt < 4; ++mt) {
        s16x8 fa = *(const s16x8*)(Ab + (wr * 64 + mt * 16 + lrow) * 128 + cx);
#pragma unroll
        for (int nt = 0; nt < 4; ++nt)
          acc[mt][nt] = __builtin_amdgcn_mfma_f32_16x16x32_bf16(fa, fb[nt], acc[mt][nt], 0, 0, 0);
      }
    }
    if (it < 15) writeA(cur ^ 1);              // cvt+write after MFMA hides HBM latency
    __syncthreads();
  }

  float* pbase = part + (size_t)kq * NN * DD;
#pragma unroll
  for (int mt = 0; mt < 4; ++mt) {
#pragma unroll
    for (int r = 0; r < 4; ++r) {
      const int i = (int)row0 + wr * 64 + mt * 16 + quad * 4 + r;
#pragma unroll
      for (int nt = 0; nt < 4; ++nt) {
        const int n = wc * 64 + nt * 16 + lrow;
        pbase[(size_t)i * DD + n] = acc[mt][nt][r];
      }
    }
  }
}

// ---- K4: out[i][n] = dinv[i]*(sum_q part[q]/127 + diag) + bias[n] ----
__global__ __launch_bounds__(256) void k_reduce(const float* __restrict__ part,
                                                const u16* __restrict__ tT,
                                                const float* __restrict__ dinv,
                                                const float* __restrict__ bias,
                                                float* __restrict__ out) {
  const int gid = blockIdx.x * 256 + threadIdx.x;   // 0 .. 262143
  const int i = gid >> 5;
  const int c = gid & 31;                            // n = 4c .. 4c+3
  const size_t idx = (size_t)i * 32 + c;
  const float inv127 = 1.0f / 127.0f;               // undo u8 fixed-point scale
  float4 p[8];
#pragma unroll
  for (int q = 0; q < 8; ++q)
    p[q] = ((const float4*)(part + (size_t)q * NN * DD))[idx];
  float4 s;
  s.x = ((p[0].x + p[1].x) + (p[2].x + p[3].x)) + ((p[4].x + p[5].x) + (p[6].x + p[7].x));
  s.y = ((p[0].y + p[1].y) + (p[2].y + p[3].y)) + ((p[4].y + p[5].y) + (p[6].y + p[7].y));
  s.z = ((p[0].z + p[1].z) + (p[2].z + p[3].z)) + ((p[4].z + p[5].z) + (p[6].z + p[7].z));
  s.w = ((p[0].w + p[1].w) + (p[2].w + p[3].w)) + ((p[4].w + p[5].w) + (p[6].w + p[7].w));
  const float4 bb = ((const float4*)bias)[c];
  const float dv = dinv[i];
  const int n = c * 4;
  float4 o;
  o.x = dv * (s.x * inv127 + bf2f(tT[(size_t)(n + 0) * NN + i])) + bb.x;
  o.y = dv * (s.y * inv127 + bf2f(tT[(size_t)(n + 1) * NN + i])) + bb.y;
  o.z = dv * (s.z * inv127 + bf2f(tT[(size_t)(n + 2) * NN + i])) + bb.z;
  o.w = dv * (s.w * inv127 + bf2f(tT[(size_t)(n + 3) * NN + i])) + bb.w;
  ((float4*)out)[idx] = o;
}

extern "C" void kernel_launch(void* const* d_in, const int* in_sizes, int n_in,
                              void* d_out, int out_size, void* d_ws, size_t ws_size,
                              hipStream_t stream) {
  const float* X    = (const float*)d_in[0];   // node_features [8192,128]
  const float* A    = (const float*)d_in[1];   // adj_matrix    [8192,8192]
  const float* W    = (const float*)d_in[2];   // weight        [128,128]
  const float* bias = (const float*)d_in[3];   // bias          [128]
  float* out = (float*)d_out;

  char* ws = (char*)d_ws;
  float* dinv        = (float*)ws;                              // 32 KB
  u16*   tT          = (u16*)(ws + 32768);                      // 2 MB
  float* part        = (float*)(ws + 32768 + 2097152);          // 32 MB (8 slices)
  unsigned char* A8  = (unsigned char*)(ws + 32768 + 2097152 + 33554432);  // 64 MB

  hipLaunchKernelGGL(k_prep,    dim3(8192), dim3(256), 0, stream, A, dinv, A8);
  hipLaunchKernelGGL(k_support, dim3(256),  dim3(256), 0, stream, X, W, dinv, tT);
  hipLaunchKernelGGL(k_gemm,    dim3(512),  dim3(256), 0, stream, A8, tT, part);
  hipLaunchKernelGGL(k_reduce,  dim3(1024), dim3(256), 0, stream, part, tT, dinv, bias, out);
}